// Round 12
// baseline (616.006 us; speedup 1.0000x reference)
//
#include <hip/hip_runtime.h>

// MultiHeadTEAttention MFMA version.
// M=8, NQ=NKV=1024, DX=512, H=8, HD=64, KHID=16, DT=2. f32 in/out, bf16 compute.
// R2: gemm via global_load_lds, 128x128 tile. R7: packed-f16 bias hinge.
// R8: hw cvt_pk; defer-rescale. R9: 512-thr attn, gl_lds K/V, dbuf.
// R10: attn XCD-grouping remap (FETCH 70->12 MB verified). R11: A-conv fused
//      into gemm1 staging; W-only prep.
// R12: revert exp2f -> __expf (R11 regression: precise exp2f has fixup code);
//      output projection FUSED into attn epilogue (per-head K-slice of O@Wo,
//      unsafeAtomicAdd f32 into d_out; prep pre-fills d_out with b_out).
//      gemm2 launch deleted.

typedef unsigned short u16;
typedef unsigned int   u32;
typedef short bf8 __attribute__((ext_vector_type(8)));   // 8 bf16 = 4 VGPR
typedef float f4  __attribute__((ext_vector_type(4)));
typedef _Float16 h2 __attribute__((ext_vector_type(2))); // packed half2

#define Mb 8
#define SCALE 0.125f
#define NTOK 4194304   // Mb*1024*512

__device__ __forceinline__ u16 f2bf(float f) {
    union { float f; u32 u; } v; v.f = f;
    u32 r = v.u + 0x7fffu + ((v.u >> 16) & 1u);   // RNE
    return (u16)(r >> 16);
}
// hardware packed f32->bf16 (RNE)
__device__ __forceinline__ u32 pk2(float a, float b) {
    u32 r;
    asm("v_cvt_pk_bf16_f32 %0, %1, %2" : "=v"(r) : "v"(a), "v"(b));
    return r;
}
__device__ __forceinline__ void gl_lds16(const u16* g, u16* l) {
    __builtin_amdgcn_global_load_lds(
        (const __attribute__((address_space(1))) u32*)g,
        (__attribute__((address_space(3))) u32*)l, 16, 0, 0);
}
__device__ __forceinline__ h2 h2_of(u32 x) {
    union { u32 u; h2 h; } c; c.u = x; return c.h;
}
__device__ __forceinline__ u32 u_of(h2 x) {
    union { h2 h; u32 u; } c; c.h = x; return c.u;
}
__device__ __forceinline__ float dot2(h2 a, h2 b, float c) {
#if __has_builtin(__builtin_amdgcn_fdot2)
    return __builtin_amdgcn_fdot2(a, b, c, false);
#else
    return fmaf((float)a[0], (float)b[0], fmaf((float)a[1], (float)b[1], c));
#endif
}

// ===========================================================================
// prep: blocks [0,256): W transpose+convert (dstW[mat][n][k] = w[mat][k][n]).
//       blocks [256,768): pre-fill d_out[tok][n] = b_out[n] (16 MB).
// ===========================================================================
struct PArgs {
    const float* ws[4];
    u16* dstW;
    const float* bias;
    float* outp;
};

__global__ __launch_bounds__(256) void prep(PArgs p) {
    __shared__ u16 tl[64][80];   // [n within tile][k within tile], padded
    const int tid = threadIdx.x;
    const int b = blockIdx.x;
    if (b < 256) {
        const int mat = b >> 6, t = b & 63;
        const int kt = t >> 3, nt = t & 7;              // 64x64 tile coords
        const float* src = p.ws[mat] + (size_t)kt * 64 * 512 + (size_t)nt * 64;
        const int r0 = tid >> 4, c4 = (tid & 15) * 4;
        #pragma unroll
        for (int rr = 0; rr < 4; ++rr) {
            const int row = r0 + rr * 16;               // k within tile
            float4 a = *(const float4*)(src + (size_t)row * 512 + c4);
            tl[c4 + 0][row] = f2bf(a.x);
            tl[c4 + 1][row] = f2bf(a.y);
            tl[c4 + 2][row] = f2bf(a.z);
            tl[c4 + 3][row] = f2bf(a.w);
        }
        __syncthreads();
        u16* dst = p.dstW + (size_t)mat * 262144 + (size_t)nt * 64 * 512 + (size_t)kt * 64;
        #pragma unroll
        for (int i = 0; i < 2; ++i) {
            const int s2 = tid + i * 256;
            const int nrow = s2 >> 3, k8 = (s2 & 7) * 8;
            *(uint4*)(dst + (size_t)nrow * 512 + k8) = *(const uint4*)&tl[nrow][k8];
        }
    } else {
        // out init: block handles 16 tok rows; thread writes 32 cols of one row
        const int bb = b - 256;
        const int tok = bb * 16 + (tid >> 4);
        const int c0 = (tid & 15) * 8;                  // float4 index base
        float* dst = p.outp + (size_t)tok * 512;
        const float4* bsrc = (const float4*)p.bias;
        #pragma unroll
        for (int i = 0; i < 8; ++i)
            *(float4*)(dst + (c0 + i) * 4) = bsrc[c0 + i];
    }
}

// ===========================================================================
// GEMM (QKV projections only now): 128x128, BK=32.
// W bf16 pre-transposed [n][k] via gl_lds (src-swizzled);
// A f32 reg-staged (cvt_pk + swizzled ds_write_b128).  (R11 version.)
// ===========================================================================
struct GArgs {
    const void*  A[3];
    const u16*   W[3];      // transposed [n][512] bf16
    void*        C[3];
    int          modeT[3];
};

__global__ __launch_bounds__(256) void gemm_mfma(GArgs g) {
    __shared__ u16 Xs[128][32];
    __shared__ u16 Ws[128][32];

    const int z   = blockIdx.z;
    const int tid = threadIdx.x;
    const int w = tid >> 6, lane = tid & 63, quad = lane >> 4, l16 = lane & 15;
    const int wm = w >> 1, wn = w & 1;
    const int n0 = blockIdx.x * 128, t0 = blockIdx.y * 128;
    const int trans = g.modeT[z];

    f4 acc[4][4];
    #pragma unroll
    for (int i = 0; i < 4; ++i)
        #pragma unroll
        for (int j = 0; j < 4; ++j) acc[i][j] = (f4)0.f;

    // W staging (gl_lds, src-swizzled)
    const int lrow  = lane >> 2;
    const int kslot = (lane & 3) ^ ((lane >> 3) & 3);
    u16* ldsW0 = &Ws[w * 32][0];
    u16* ldsW1 = &Ws[w * 32 + 16][0];
    const u16* gW0 = g.W[z] + (size_t)(n0 + w * 32 + lrow) * 512 + kslot * 8;
    const u16* gW1 = gW0 + 16 * 512;

    // A staging (f32 reg-stage + swizzled ds_write)
    const int arow_s = tid >> 1, ah = tid & 1;
    const float* aF = (const float*)g.A[z] + (size_t)(t0 + arow_s) * 512 + ah * 16;
    const int s_sw = (arow_s >> 1) & 3;
    u16* aw0 = &Xs[arow_s][((2 * ah)     ^ s_sw) * 8];
    u16* aw1 = &Xs[arow_s][((2 * ah + 1) ^ s_sw) * 8];

    const int rslot = (quad ^ ((l16 >> 1) & 3)) * 8;

    for (int kc = 0; kc < 512; kc += 32) {
        __syncthreads();
        {
            float4 f0 = *(const float4*)(aF + kc);
            float4 f1 = *(const float4*)(aF + kc + 4);
            float4 f2 = *(const float4*)(aF + kc + 8);
            float4 f3 = *(const float4*)(aF + kc + 12);
            uint4 v0, v1;
            v0.x = pk2(f0.x, f0.y); v0.y = pk2(f0.z, f0.w);
            v0.z = pk2(f1.x, f1.y); v0.w = pk2(f1.z, f1.w);
            v1.x = pk2(f2.x, f2.y); v1.y = pk2(f2.z, f2.w);
            v1.z = pk2(f3.x, f3.y); v1.w = pk2(f3.z, f3.w);
            *(uint4*)aw0 = v0;
            *(uint4*)aw1 = v1;
        }
        gl_lds16(gW0 + kc, ldsW0);
        gl_lds16(gW1 + kc, ldsW1);
        __syncthreads();

        const u16* Abase = trans ? &Xs[0][0] : &Ws[0][0];
        const u16* Bbase = trans ? &Ws[0][0] : &Xs[0][0];
        const int arow = (trans ? wm : wn) * 64;
        const int brow = (trans ? wn : wm) * 64;
        bf8 af[4], bf[4];
        #pragma unroll
        for (int i = 0; i < 4; ++i)
            af[i] = *(const bf8*)(Abase + (arow + i * 16 + l16) * 32 + rslot);
        #pragma unroll
        for (int j = 0; j < 4; ++j)
            bf[j] = *(const bf8*)(Bbase + (brow + j * 16 + l16) * 32 + rslot);
        #pragma unroll
        for (int i = 0; i < 4; ++i)
            #pragma unroll
            for (int j = 0; j < 4; ++j)
                acc[i][j] = __builtin_amdgcn_mfma_f32_16x16x32_bf16(af[i], bf[j], acc[i][j], 0, 0, 0);
    }

    // ---- epilogue (bf16 outputs only) ----
    if (!trans) {
        u16* C = (u16*)g.C[z];
        #pragma unroll
        for (int i = 0; i < 4; ++i) {
            const int nb = n0 + wn * 64 + i * 16 + quad * 4;
            #pragma unroll
            for (int j = 0; j < 4; ++j) {
                const int tok = t0 + wm * 64 + j * 16 + l16;
                uint2 pw;
                pw.x = pk2(acc[i][j][0], acc[i][j][1]);
                pw.y = pk2(acc[i][j][2], acc[i][j][3]);
                *(uint2*)&C[(size_t)tok * 512 + nb] = pw;
            }
        }
    } else {
        u16* Vt = (u16*)g.C[z];
        #pragma unroll
        for (int i = 0; i < 4; ++i) {
            const int tokb = t0 + wm * 64 + i * 16 + quad * 4;
            const int mb = tokb >> 10, tb = tokb & 1023;
            #pragma unroll
            for (int j = 0; j < 4; ++j) {
                const int n = n0 + wn * 64 + j * 16 + l16;
                uint2 pw;
                pw.x = pk2(acc[i][j][0], acc[i][j][1]);
                pw.y = pk2(acc[i][j][2], acc[i][j][3]);
                *(uint2*)&Vt[(size_t)mb * 524288 + (size_t)n * 1024 + tb] = pw;
            }
        }
    }
}

// ===========================================================================
// Fused flash attention + output projection. R10 attn structure (__expf).
// Epilogue: normalized O (bf16) -> wave-private LDS (reuse sP) -> B-fragments;
// A-fragments = Wt[n][h*64+d] straight from global (L2-hot, 256 KB shared);
// 2 MFMA per 16-n chunk; unsafeAtomicAdd f32 into pre-biased d_out.
// ===========================================================================
__global__ __launch_bounds__(512) void attn_mfma(
    const u16* __restrict__ Q, const u16* __restrict__ K,
    const u16* __restrict__ Vt,
    const float* __restrict__ tqp, const float* __restrict__ tkp,
    const float* __restrict__ kw1, const float* __restrict__ kb1,
    const float* __restrict__ kw2,
    const u16* __restrict__ Wo, float* __restrict__ Oout)
{
    __shared__ u16 sK[2][8][64][8];   // [buf][d-octet][key][8 bf16]
    __shared__ u16 sV[2][8][64][8];   // [buf][key-octet][d][8 bf16]
    __shared__ u32 sv2[2][8][68];     // [buf][c-pair][key] half2
    __shared__ u16 sP[8][16][68];     // per-wave P [q][key], +4 pad

    const int tid = threadIdx.x;
    const int w = tid >> 6, lane = tid & 63, quad = lane >> 4, l16 = lane & 15;
    // XCD-grouping remap (R10): all 8 head-blocks of batch m land on XCD m
    const int b = (blockIdx.z * 8 + blockIdx.y) * 8 + blockIdx.x;
    const int xc = b & 7, j = b >> 3;
    const int hm = xc * 8 + (j & 7);
    const int qt = j >> 3;
    const int h = hm & 7, m = hm >> 3;
    const int q0 = qt * 128;
    const size_t qtok = (size_t)m * 1024 + q0 + w * 16 + l16;

    bf8 qf[2];
    {
        const u16* qp = Q + qtok * 512 + h * 64 + quad * 8;
        qf[0] = *(const bf8*)qp;
        qf[1] = *(const bf8*)(qp + 32);
    }
    h2 u2[8], w2p[8];
    {
        const float t0v = tqp[qtok * 2], t1v = tqp[qtok * 2 + 1];
        #pragma unroll
        for (int cp = 0; cp < 8; ++cp) {
            const int c0 = 2 * cp, c1 = 2 * cp + 1;
            float ua = fmaf(t0v, kw1[c0], fmaf(t1v, kw1[16 + c0], kb1[c0]));
            float ub = fmaf(t0v, kw1[c1], fmaf(t1v, kw1[16 + c1], kb1[c1]));
            u2[cp][0]  = (_Float16)ua;              u2[cp][1]  = (_Float16)ub;
            w2p[cp][0] = (_Float16)kw2[c0 * 8 + h]; w2p[cp][1] = (_Float16)kw2[c1 * 8 + h];
        }
    }
    const float w0a = kw1[2 * w],     w1a = kw1[16 + 2 * w];
    const float w0b = kw1[2 * w + 1], w1b = kw1[16 + 2 * w + 1];

    const u16* gK = K + ((size_t)m * 1024 + lane) * 512 + h * 64 + w * 8;
    const u16* gV = Vt + (size_t)m * 524288 + (size_t)(h * 64 + lane) * 1024 + w * 8;
    const float* gT = tkp + (size_t)m * 2048 + lane * 2;

    float mrun = -1e30f, lrun = 0.f;
    f4 o[4];
    #pragma unroll
    for (int d = 0; d < 4; ++d) o[d] = (f4)0.f;

    auto STAGE = [&](int kt2, int nb) {
        const int k0n = kt2 * 64;
        float2 t = *(const float2*)(gT + k0n * 2);
        h2 pv;
        pv[0] = (_Float16)fmaf(t.x, w0a, t.y * w1a);
        pv[1] = (_Float16)fmaf(t.x, w0b, t.y * w1b);
        sv2[nb][w][lane] = u_of(pv);
        gl_lds16(gK + (size_t)k0n * 512, &sK[nb][w][0][0]);
        gl_lds16(gV + k0n,               &sV[nb][w][0][0]);
    };

    STAGE(0, 0);
    __syncthreads();

    int cur = 0;
    for (int kt = 0; kt < 16; ++kt) {
        if (kt < 15) STAGE(kt + 1, cur ^ 1);

        // ---- S^T = K·Q^T ----
        f4 s[4];
        #pragma unroll
        for (int msub = 0; msub < 4; ++msub) {
            bf8 kf0 = *(const bf8*)&sK[cur][quad][msub * 16 + l16][0];
            bf8 kf1 = *(const bf8*)&sK[cur][4 + quad][msub * 16 + l16][0];
            s[msub] = __builtin_amdgcn_mfma_f32_16x16x32_bf16(kf0, qf[0], (f4)0.f, 0, 0, 0);
            s[msub] = __builtin_amdgcn_mfma_f32_16x16x32_bf16(kf1, qf[1], s[msub], 0, 0, 0);
        }
        // ---- bias (packed f16) ----
        #pragma unroll
        for (int msub = 0; msub < 4; ++msub) {
            const int kb = msub * 16 + quad * 4;
            f4 b2 = (f4)0.f;
            #pragma unroll
            for (int cp = 0; cp < 8; ++cp) {
                uint4 vv = *(const uint4*)&sv2[cur][cp][kb];
                const h2 uc = u2[cp], wc = w2p[cp];
                const h2 z = (h2)(_Float16)0.f;
                h2 d0 = uc - h2_of(vv.x);
                h2 d1 = uc - h2_of(vv.y);
                h2 d2 = uc - h2_of(vv.z);
                h2 d3 = uc - h2_of(vv.w);
                d0 = __builtin_elementwise_max(d0, z);
                d1 = __builtin_elementwise_max(d1, z);
                d2 = __builtin_elementwise_max(d2, z);
                d3 = __builtin_elementwise_max(d3, z);
                b2[0] = dot2(d0, wc, b2[0]);
                b2[1] = dot2(d1, wc, b2[1]);
                b2[2] = dot2(d2, wc, b2[2]);
                b2[3] = dot2(d3, wc, b2[3]);
            }
            s[msub] = s[msub] * SCALE + b2;
        }
        // ---- online softmax (__expf) ----
        float mx = -1e30f;
        #pragma unroll
        for (int msub = 0; msub < 4; ++msub) {
            mx = fmaxf(mx, fmaxf(fmaxf(s[msub][0], s[msub][1]),
                                 fmaxf(s[msub][2], s[msub][3])));
        }
        mx = fmaxf(mx, __shfl_xor(mx, 16));
        mx = fmaxf(mx, __shfl_xor(mx, 32));
        const float mnew = fmaxf(mrun, mx);
        float ps = 0.f;
        #pragma unroll
        for (int msub = 0; msub < 4; ++msub) {
            #pragma unroll
            for (int r = 0; r < 4; ++r) {
                float p = __expf(s[msub][r] - mnew);
                s[msub][r] = p;
                ps += p;
            }
        }
        ps += __shfl_xor(ps, 16);
        ps += __shfl_xor(ps, 32);
        if (__all(mx <= mrun)) {
            lrun += ps;             // alpha == 1 exactly
        } else {
            const float alpha = __expf(mrun - mnew);
            lrun = lrun * alpha + ps;
            mrun = mnew;
            #pragma unroll
            for (int d = 0; d < 4; ++d) o[d] = o[d] * alpha;
        }
        // ---- write P (bf16) to wave-private sP[q][key] ----
        #pragma unroll
        for (int msub = 0; msub < 4; ++msub) {
            uint2 pw;
            pw.x = pk2(s[msub][0], s[msub][1]);
            pw.y = pk2(s[msub][2], s[msub][3]);
            *(uint2*)&sP[w][l16][msub * 16 + quad * 4] = pw;
        }
        // ---- O^T += Vt·P^T ----
        #pragma unroll
        for (int dsub = 0; dsub < 4; ++dsub) {
            #pragma unroll
            for (int kc2 = 0; kc2 < 2; ++kc2) {
                bf8 vf = *(const bf8*)&sV[cur][kc2 * 4 + quad][dsub * 16 + l16][0];
                bf8 pf = *(const bf8*)&sP[w][l16][kc2 * 32 + quad * 8];
                o[dsub] = __builtin_amdgcn_mfma_f32_16x16x32_bf16(vf, pf, o[dsub], 0, 0, 0);
            }
        }

        if (kt < 15) __syncthreads();
        cur ^= 1;
    }

    // ---- fused output projection epilogue ----
    // normalized O (bf16) into wave-private LDS, [q][d] layout (reuse sP)
    const float inv = 1.f / lrun;
    #pragma unroll
    for (int dsub = 0; dsub < 4; ++dsub) {
        uint2 pw;
        pw.x = pk2(o[dsub][0] * inv, o[dsub][1] * inv);
        pw.y = pk2(o[dsub][2] * inv, o[dsub][3] * inv);
        *(uint2*)&sP[w][l16][dsub * 16 + quad * 4] = pw;
    }
    // B-fragments: rows = tok (l16), k = d = quad*8 (+32 for 2nd k-step)
    bf8 of0 = *(const bf8*)&sP[w][l16][quad * 8];
    bf8 of1 = *(const bf8*)&sP[w][l16][32 + quad * 8];
    // out[tok][n] += sum_d O[tok][h*64+d] * Wo[n][h*64+d]
    float* outp = Oout + qtok * 512;
    const u16* woA = Wo + (size_t)l16 * 512 + h * 64 + quad * 8;
    #pragma unroll 4
    for (int nf = 0; nf < 32; ++nf) {
        const u16* wp = woA + (size_t)nf * 16 * 512;
        bf8 af0 = *(const bf8*)wp;
        bf8 af1 = *(const bf8*)(wp + 32);
        f4 a = __builtin_amdgcn_mfma_f32_16x16x32_bf16(af0, of0, (f4)0.f, 0, 0, 0);
        a = __builtin_amdgcn_mfma_f32_16x16x32_bf16(af1, of1, a, 0, 0, 0);
        const int nb = nf * 16 + quad * 4;
        #pragma unroll
        for (int r = 0; r < 4; ++r)
            unsafeAtomicAdd(&outp[nb + r], a[r]);
    }
}

// ===========================================================================
extern "C" void kernel_launch(void* const* d_in, const int* in_sizes, int n_in,
                              void* d_out, int out_size, void* d_ws, size_t ws_size,
                              hipStream_t stream) {
    const float* xq    = (const float*)d_in[0];
    const float* xk    = (const float*)d_in[1];
    const float* xv    = (const float*)d_in[2];
    const float* tq    = (const float*)d_in[3];
    const float* tk    = (const float*)d_in[4];
    const float* w_q   = (const float*)d_in[5];
    const float* w_k   = (const float*)d_in[6];
    const float* w_v   = (const float*)d_in[7];
    const float* w_out = (const float*)d_in[8];
    const float* b_out = (const float*)d_in[9];
    const float* kw1   = (const float*)d_in[10];
    const float* kb1   = (const float*)d_in[11];
    const float* kw2   = (const float*)d_in[12];

    // workspace: Q | K | Vt | Wq | Wk | Wv | Wo
    u16* Q  = (u16*)d_ws;
    u16* Kp = Q  + NTOK;
    u16* Vt = Kp + NTOK;
    u16* Wq = Vt + NTOK;
    u16* Wk = Wq + 262144;
    u16* Wv = Wk + 262144;
    u16* Wo = Wv + 262144;

    // --- prep: W transpose+convert (256 blocks) + out = b_out (512 blocks) ---
    PArgs p;
    p.ws[0] = w_q; p.ws[1] = w_k; p.ws[2] = w_v; p.ws[3] = w_out;
    p.dstW = Wq;
    p.bias = b_out;
    p.outp = (float*)d_out;
    prep<<<dim3(768), 256, 0, stream>>>(p);

    // --- QKV projections (A = f32 inputs, conversion fused into staging) ---
    GArgs gq;
    gq.A[0] = xq;  gq.A[1] = xk;  gq.A[2] = xv;
    gq.W[0] = Wq;  gq.W[1] = Wk;  gq.W[2] = Wv;
    gq.C[0] = Q;   gq.C[1] = Kp;  gq.C[2] = Vt;
    gq.modeT[0] = 0; gq.modeT[1] = 0; gq.modeT[2] = 1;
    gemm_mfma<<<dim3(4, 64, 3), 256, 0, stream>>>(gq);

    // --- fused attention + output projection ---
    attn_mfma<<<dim3(8, 8, Mb), 512, 0, stream>>>(Q, Kp, Vt, tq, tk,
                                                  kw1, kb1, kw2,
                                                  Wo, (float*)d_out);
}

// Round 13
// 248.196 us; speedup vs baseline: 2.4819x; 2.4819x over previous
//
#include <hip/hip_runtime.h>

// MultiHeadTEAttention MFMA version.
// M=8, NQ=NKV=1024, DX=512, H=8, HD=64, KHID=16, DT=2. f32 in/out, bf16 compute.
// R2: gemm via global_load_lds, 128x128 tile. R7: packed-f16 bias hinge.
// R8: hw cvt_pk; defer-rescale. R9: 512-thr attn, gl_lds K/V, dbuf.
// R10: attn XCD-grouping remap (FETCH 70->12 MB verified; 98.5 us attn).
// R11: A-conv fused into gemm1 staging; W-only prep.
// R13: revert R12's fused out-proj (atomic WRITE_SIZE blow-up: 537 MB);
//      separate gemm2 restored. attn = R10-exact. gemm1 A-loads software-
//      pipelined (T14 split: next-step f32 loads issued before the barrier,
//      so barrier drains A and W latency in parallel).

typedef unsigned short u16;
typedef unsigned int   u32;
typedef short bf8 __attribute__((ext_vector_type(8)));   // 8 bf16 = 4 VGPR
typedef float f4  __attribute__((ext_vector_type(4)));
typedef _Float16 h2 __attribute__((ext_vector_type(2))); // packed half2

#define Mb 8
#define SCALE 0.125f
#define NTOK 4194304   // Mb*1024*512

__device__ __forceinline__ u16 f2bf(float f) {
    union { float f; u32 u; } v; v.f = f;
    u32 r = v.u + 0x7fffu + ((v.u >> 16) & 1u);   // RNE
    return (u16)(r >> 16);
}
// hardware packed f32->bf16 (RNE)
__device__ __forceinline__ u32 pk2(float a, float b) {
    u32 r;
    asm("v_cvt_pk_bf16_f32 %0, %1, %2" : "=v"(r) : "v"(a), "v"(b));
    return r;
}
__device__ __forceinline__ void gl_lds16(const u16* g, u16* l) {
    __builtin_amdgcn_global_load_lds(
        (const __attribute__((address_space(1))) u32*)g,
        (__attribute__((address_space(3))) u32*)l, 16, 0, 0);
}
__device__ __forceinline__ h2 h2_of(u32 x) {
    union { u32 u; h2 h; } c; c.u = x; return c.h;
}
__device__ __forceinline__ u32 u_of(h2 x) {
    union { h2 h; u32 u; } c; c.h = x; return c.u;
}
__device__ __forceinline__ float dot2(h2 a, h2 b, float c) {
#if __has_builtin(__builtin_amdgcn_fdot2)
    return __builtin_amdgcn_fdot2(a, b, c, false);
#else
    return fmaf((float)a[0], (float)b[0], fmaf((float)a[1], (float)b[1], c));
#endif
}

// ===========================================================================
// prep: W transpose+convert only. dstW[mat][n][k] = w[mat][k][n]. 256 blocks.
// ===========================================================================
struct PArgs {
    const float* ws[4];
    u16* dstW;
};

__global__ __launch_bounds__(256) void prep(PArgs p) {
    __shared__ u16 tl[64][80];   // [n within tile][k within tile], padded
    const int tid = threadIdx.x;
    const int b = blockIdx.x;
    const int mat = b >> 6, t = b & 63;
    const int kt = t >> 3, nt = t & 7;              // 64x64 tile coords
    const float* src = p.ws[mat] + (size_t)kt * 64 * 512 + (size_t)nt * 64;
    const int r0 = tid >> 4, c4 = (tid & 15) * 4;
    #pragma unroll
    for (int rr = 0; rr < 4; ++rr) {
        const int row = r0 + rr * 16;               // k within tile
        float4 a = *(const float4*)(src + (size_t)row * 512 + c4);
        tl[c4 + 0][row] = f2bf(a.x);
        tl[c4 + 1][row] = f2bf(a.y);
        tl[c4 + 2][row] = f2bf(a.z);
        tl[c4 + 3][row] = f2bf(a.w);
    }
    __syncthreads();
    u16* dst = p.dstW + (size_t)mat * 262144 + (size_t)nt * 64 * 512 + (size_t)kt * 64;
    #pragma unroll
    for (int i = 0; i < 2; ++i) {
        const int s2 = tid + i * 256;
        const int nrow = s2 >> 3, k8 = (s2 & 7) * 8;
        *(uint4*)(dst + (size_t)nrow * 512 + k8) = *(const uint4*)&tl[nrow][k8];
    }
}

// ===========================================================================
// GEMM: C = A[8192x512] @ W[512x512] (+bias). 128x128, BK=32.
// W bf16 pre-transposed [n][k] via gl_lds (src-swizzled).
// A path (af32=1): f32 reg-staged, software-pipelined -- loads for step k+1
//   issue before the barrier so the drain covers A and W latency together;
//   cvt_pk + swizzled ds_write_b128 happen from ready registers.
// A path (af32=0): bf16 via gl_lds (src-swizzled).
// ===========================================================================
struct GArgs {
    const void*  A[3];
    const u16*   W[3];      // transposed [n][512] bf16
    void*        C[3];
    const float* bias;
    int          modeT[3];
    int          outf32;
    int          af32;
};

__global__ __launch_bounds__(256) void gemm_mfma(GArgs g) {
    __shared__ u16 Xs[128][32];
    __shared__ u16 Ws[128][32];

    const int z   = blockIdx.z;
    const int tid = threadIdx.x;
    const int w = tid >> 6, lane = tid & 63, quad = lane >> 4, l16 = lane & 15;
    const int wm = w >> 1, wn = w & 1;
    const int n0 = blockIdx.x * 128, t0 = blockIdx.y * 128;
    const int trans = g.modeT[z];

    f4 acc[4][4];
    #pragma unroll
    for (int i = 0; i < 4; ++i)
        #pragma unroll
        for (int j = 0; j < 4; ++j) acc[i][j] = (f4)0.f;

    // W staging (gl_lds, src-swizzled)
    const int lrow  = lane >> 2;
    const int kslot = (lane & 3) ^ ((lane >> 3) & 3);
    u16* ldsW0 = &Ws[w * 32][0];
    u16* ldsW1 = &Ws[w * 32 + 16][0];
    const u16* gW0 = g.W[z] + (size_t)(n0 + w * 32 + lrow) * 512 + kslot * 8;
    const u16* gW1 = gW0 + 16 * 512;

    // A bf16 path (gl_lds)
    u16* ldsX0 = &Xs[w * 32][0];
    u16* ldsX1 = &Xs[w * 32 + 16][0];
    const u16* gA0 = (const u16*)g.A[z] + (size_t)(t0 + w * 32 + lrow) * 512 + kslot * 8;
    const u16* gA1 = gA0 + 16 * 512;

    // A f32 path (reg-stage, pipelined)
    const int arow_s = tid >> 1, ah = tid & 1;
    const float* aF = (const float*)g.A[z] + (size_t)(t0 + arow_s) * 512 + ah * 16;
    const int s_sw = (arow_s >> 1) & 3;
    u16* aw0 = &Xs[arow_s][((2 * ah)     ^ s_sw) * 8];
    u16* aw1 = &Xs[arow_s][((2 * ah + 1) ^ s_sw) * 8];

    const int rslot = (quad ^ ((l16 >> 1) & 3)) * 8;

    float4 f0, f1, f2, f3;
    if (g.af32) {
        f0 = *(const float4*)(aF + 0);
        f1 = *(const float4*)(aF + 4);
        f2 = *(const float4*)(aF + 8);
        f3 = *(const float4*)(aF + 12);
    }

    for (int kc = 0; kc < 512; kc += 32) {
        __syncthreads();
        if (g.af32) {
            uint4 v0, v1;
            v0.x = pk2(f0.x, f0.y); v0.y = pk2(f0.z, f0.w);
            v0.z = pk2(f1.x, f1.y); v0.w = pk2(f1.z, f1.w);
            v1.x = pk2(f2.x, f2.y); v1.y = pk2(f2.z, f2.w);
            v1.z = pk2(f3.x, f3.y); v1.w = pk2(f3.z, f3.w);
            *(uint4*)aw0 = v0;
            *(uint4*)aw1 = v1;
        } else {
            gl_lds16(gA0 + kc, ldsX0);
            gl_lds16(gA1 + kc, ldsX1);
        }
        gl_lds16(gW0 + kc, ldsW0);
        gl_lds16(gW1 + kc, ldsW1);
        if (g.af32 && kc + 32 < 512) {
            // prefetch next step's A -- drains in parallel with W at barrier
            f0 = *(const float4*)(aF + kc + 32);
            f1 = *(const float4*)(aF + kc + 36);
            f2 = *(const float4*)(aF + kc + 40);
            f3 = *(const float4*)(aF + kc + 44);
        }
        __syncthreads();

        const u16* Abase = trans ? &Xs[0][0] : &Ws[0][0];
        const u16* Bbase = trans ? &Ws[0][0] : &Xs[0][0];
        const int arow = (trans ? wm : wn) * 64;
        const int brow = (trans ? wn : wm) * 64;
        bf8 af[4], bf[4];
        #pragma unroll
        for (int i = 0; i < 4; ++i)
            af[i] = *(const bf8*)(Abase + (arow + i * 16 + l16) * 32 + rslot);
        #pragma unroll
        for (int j = 0; j < 4; ++j)
            bf[j] = *(const bf8*)(Bbase + (brow + j * 16 + l16) * 32 + rslot);
        #pragma unroll
        for (int i = 0; i < 4; ++i)
            #pragma unroll
            for (int j = 0; j < 4; ++j)
                acc[i][j] = __builtin_amdgcn_mfma_f32_16x16x32_bf16(af[i], bf[j], acc[i][j], 0, 0, 0);
    }

    // ---- epilogue ----
    if (g.outf32) {
        float* Co = (float*)g.C[z];
        #pragma unroll
        for (int i = 0; i < 4; ++i) {
            const int nb = n0 + wn * 64 + i * 16 + quad * 4;
            float4 bv = *(const float4*)&g.bias[nb];
            #pragma unroll
            for (int j = 0; j < 4; ++j) {
                const int tok = t0 + wm * 64 + j * 16 + l16;
                float4 st;
                st.x = acc[i][j][0] + bv.x; st.y = acc[i][j][1] + bv.y;
                st.z = acc[i][j][2] + bv.z; st.w = acc[i][j][3] + bv.w;
                *(float4*)&Co[(size_t)tok * 512 + nb] = st;
            }
        }
    } else if (!trans) {
        u16* C = (u16*)g.C[z];
        #pragma unroll
        for (int i = 0; i < 4; ++i) {
            const int nb = n0 + wn * 64 + i * 16 + quad * 4;
            #pragma unroll
            for (int j = 0; j < 4; ++j) {
                const int tok = t0 + wm * 64 + j * 16 + l16;
                uint2 pw;
                pw.x = pk2(acc[i][j][0], acc[i][j][1]);
                pw.y = pk2(acc[i][j][2], acc[i][j][3]);
                *(uint2*)&C[(size_t)tok * 512 + nb] = pw;
            }
        }
    } else {
        u16* Vt = (u16*)g.C[z];
        #pragma unroll
        for (int i = 0; i < 4; ++i) {
            const int tokb = t0 + wm * 64 + i * 16 + quad * 4;
            const int mb = tokb >> 10, tb = tokb & 1023;
            #pragma unroll
            for (int j = 0; j < 4; ++j) {
                const int n = n0 + wn * 64 + j * 16 + l16;
                uint2 pw;
                pw.x = pk2(acc[i][j][0], acc[i][j][1]);
                pw.y = pk2(acc[i][j][2], acc[i][j][3]);
                *(uint2*)&Vt[(size_t)mb * 524288 + (size_t)n * 1024 + tb] = pw;
            }
        }
    }
}

// ===========================================================================
// Fused flash attention (MFMA). R10-exact: 512-thr blocks (128 q), gl_lds K/V,
// double-buffered, one __syncthreads per tile, XCD-grouping remap, packed-f16
// bias hinge, __expf softmax, exact defer-rescale.
// ===========================================================================
__global__ __launch_bounds__(512) void attn_mfma(
    const u16* __restrict__ Q, const u16* __restrict__ K,
    const u16* __restrict__ Vt,
    const float* __restrict__ tqp, const float* __restrict__ tkp,
    const float* __restrict__ kw1, const float* __restrict__ kb1,
    const float* __restrict__ kw2,
    u16* __restrict__ O)
{
    __shared__ u16 sK[2][8][64][8];   // [buf][d-octet][key][8 bf16]
    __shared__ u16 sV[2][8][64][8];   // [buf][key-octet][d][8 bf16]
    __shared__ u32 sv2[2][8][68];     // [buf][c-pair][key] half2
    __shared__ u16 sP[8][16][68];     // per-wave P [q][key], +4 pad

    const int tid = threadIdx.x;
    const int w = tid >> 6, lane = tid & 63, quad = lane >> 4, l16 = lane & 15;
    // XCD-grouping remap (R10, FETCH-verified)
    const int b = (blockIdx.z * 8 + blockIdx.y) * 8 + blockIdx.x;
    const int xc = b & 7, j = b >> 3;
    const int hm = xc * 8 + (j & 7);
    const int qt = j >> 3;
    const int h = hm & 7, m = hm >> 3;
    const int q0 = qt * 128;
    const size_t qtok = (size_t)m * 1024 + q0 + w * 16 + l16;

    bf8 qf[2];
    {
        const u16* qp = Q + qtok * 512 + h * 64 + quad * 8;
        qf[0] = *(const bf8*)qp;
        qf[1] = *(const bf8*)(qp + 32);
    }
    h2 u2[8], w2p[8];
    {
        const float t0v = tqp[qtok * 2], t1v = tqp[qtok * 2 + 1];
        #pragma unroll
        for (int cp = 0; cp < 8; ++cp) {
            const int c0 = 2 * cp, c1 = 2 * cp + 1;
            float ua = fmaf(t0v, kw1[c0], fmaf(t1v, kw1[16 + c0], kb1[c0]));
            float ub = fmaf(t0v, kw1[c1], fmaf(t1v, kw1[16 + c1], kb1[c1]));
            u2[cp][0]  = (_Float16)ua;              u2[cp][1]  = (_Float16)ub;
            w2p[cp][0] = (_Float16)kw2[c0 * 8 + h]; w2p[cp][1] = (_Float16)kw2[c1 * 8 + h];
        }
    }
    const float w0a = kw1[2 * w],     w1a = kw1[16 + 2 * w];
    const float w0b = kw1[2 * w + 1], w1b = kw1[16 + 2 * w + 1];

    const u16* gK = K + ((size_t)m * 1024 + lane) * 512 + h * 64 + w * 8;
    const u16* gV = Vt + (size_t)m * 524288 + (size_t)(h * 64 + lane) * 1024 + w * 8;
    const float* gT = tkp + (size_t)m * 2048 + lane * 2;

    float mrun = -1e30f, lrun = 0.f;
    f4 o[4];
    #pragma unroll
    for (int d = 0; d < 4; ++d) o[d] = (f4)0.f;

    auto STAGE = [&](int kt2, int nb) {
        const int k0n = kt2 * 64;
        float2 t = *(const float2*)(gT + k0n * 2);
        h2 pv;
        pv[0] = (_Float16)fmaf(t.x, w0a, t.y * w1a);
        pv[1] = (_Float16)fmaf(t.x, w0b, t.y * w1b);
        sv2[nb][w][lane] = u_of(pv);
        gl_lds16(gK + (size_t)k0n * 512, &sK[nb][w][0][0]);
        gl_lds16(gV + k0n,               &sV[nb][w][0][0]);
    };

    STAGE(0, 0);
    __syncthreads();

    int cur = 0;
    for (int kt = 0; kt < 16; ++kt) {
        if (kt < 15) STAGE(kt + 1, cur ^ 1);

        // ---- S^T = K·Q^T ----
        f4 s[4];
        #pragma unroll
        for (int msub = 0; msub < 4; ++msub) {
            bf8 kf0 = *(const bf8*)&sK[cur][quad][msub * 16 + l16][0];
            bf8 kf1 = *(const bf8*)&sK[cur][4 + quad][msub * 16 + l16][0];
            s[msub] = __builtin_amdgcn_mfma_f32_16x16x32_bf16(kf0, qf[0], (f4)0.f, 0, 0, 0);
            s[msub] = __builtin_amdgcn_mfma_f32_16x16x32_bf16(kf1, qf[1], s[msub], 0, 0, 0);
        }
        // ---- bias (packed f16) ----
        #pragma unroll
        for (int msub = 0; msub < 4; ++msub) {
            const int kb = msub * 16 + quad * 4;
            f4 b2 = (f4)0.f;
            #pragma unroll
            for (int cp = 0; cp < 8; ++cp) {
                uint4 vv = *(const uint4*)&sv2[cur][cp][kb];
                const h2 uc = u2[cp], wc = w2p[cp];
                const h2 z = (h2)(_Float16)0.f;
                h2 d0 = uc - h2_of(vv.x);
                h2 d1 = uc - h2_of(vv.y);
                h2 d2 = uc - h2_of(vv.z);
                h2 d3 = uc - h2_of(vv.w);
                d0 = __builtin_elementwise_max(d0, z);
                d1 = __builtin_elementwise_max(d1, z);
                d2 = __builtin_elementwise_max(d2, z);
                d3 = __builtin_elementwise_max(d3, z);
                b2[0] = dot2(d0, wc, b2[0]);
                b2[1] = dot2(d1, wc, b2[1]);
                b2[2] = dot2(d2, wc, b2[2]);
                b2[3] = dot2(d3, wc, b2[3]);
            }
            s[msub] = s[msub] * SCALE + b2;
        }
        // ---- online softmax (__expf) ----
        float mx = -1e30f;
        #pragma unroll
        for (int msub = 0; msub < 4; ++msub) {
            mx = fmaxf(mx, fmaxf(fmaxf(s[msub][0], s[msub][1]),
                                 fmaxf(s[msub][2], s[msub][3])));
        }
        mx = fmaxf(mx, __shfl_xor(mx, 16));
        mx = fmaxf(mx, __shfl_xor(mx, 32));
        const float mnew = fmaxf(mrun, mx);
        float ps = 0.f;
        #pragma unroll
        for (int msub = 0; msub < 4; ++msub) {
            #pragma unroll
            for (int r = 0; r < 4; ++r) {
                float p = __expf(s[msub][r] - mnew);
                s[msub][r] = p;
                ps += p;
            }
        }
        ps += __shfl_xor(ps, 16);
        ps += __shfl_xor(ps, 32);
        if (__all(mx <= mrun)) {
            lrun += ps;             // alpha == 1 exactly
        } else {
            const float alpha = __expf(mrun - mnew);
            lrun = lrun * alpha + ps;
            mrun = mnew;
            #pragma unroll
            for (int d = 0; d < 4; ++d) o[d] = o[d] * alpha;
        }
        // ---- write P (bf16) to wave-private sP[q][key] ----
        #pragma unroll
        for (int msub = 0; msub < 4; ++msub) {
            uint2 pw;
            pw.x = pk2(s[msub][0], s[msub][1]);
            pw.y = pk2(s[msub][2], s[msub][3]);
            *(uint2*)&sP[w][l16][msub * 16 + quad * 4] = pw;
        }
        // ---- O^T += Vt·P^T ----
        #pragma unroll
        for (int dsub = 0; dsub < 4; ++dsub) {
            #pragma unroll
            for (int kc2 = 0; kc2 < 2; ++kc2) {
                bf8 vf = *(const bf8*)&sV[cur][kc2 * 4 + quad][dsub * 16 + l16][0];
                bf8 pf = *(const bf8*)&sP[w][l16][kc2 * 32 + quad * 8];
                o[dsub] = __builtin_amdgcn_mfma_f32_16x16x32_bf16(vf, pf, o[dsub], 0, 0, 0);
            }
        }

        if (kt < 15) __syncthreads();
        cur ^= 1;
    }

    // ---- epilogue: O[tok][h*64 + d] = o/l ----
    const float inv = 1.f / lrun;
    #pragma unroll
    for (int dsub = 0; dsub < 4; ++dsub) {
        uint2 pw;
        pw.x = pk2(o[dsub][0] * inv, o[dsub][1] * inv);
        pw.y = pk2(o[dsub][2] * inv, o[dsub][3] * inv);
        *(uint2*)&O[qtok * 512 + h * 64 + dsub * 16 + quad * 4] = pw;
    }
}

// ===========================================================================
extern "C" void kernel_launch(void* const* d_in, const int* in_sizes, int n_in,
                              void* d_out, int out_size, void* d_ws, size_t ws_size,
                              hipStream_t stream) {
    const float* xq    = (const float*)d_in[0];
    const float* xk    = (const float*)d_in[1];
    const float* xv    = (const float*)d_in[2];
    const float* tq    = (const float*)d_in[3];
    const float* tk    = (const float*)d_in[4];
    const float* w_q   = (const float*)d_in[5];
    const float* w_k   = (const float*)d_in[6];
    const float* w_v   = (const float*)d_in[7];
    const float* w_out = (const float*)d_in[8];
    const float* b_out = (const float*)d_in[9];
    const float* kw1   = (const float*)d_in[10];
    const float* kb1   = (const float*)d_in[11];
    const float* kw2   = (const float*)d_in[12];

    // workspace: Q | K | Vt | O | Wq | Wk | Wv | Wo
    u16* Q  = (u16*)d_ws;
    u16* Kp = Q  + NTOK;
    u16* Vt = Kp + NTOK;
    u16* O  = Vt + NTOK;
    u16* Wq = O  + NTOK;
    u16* Wk = Wq + 262144;
    u16* Wv = Wk + 262144;
    u16* Wo = Wv + 262144;

    // --- prep: W transpose+convert (256 blocks) ---
    PArgs p;
    p.ws[0] = w_q; p.ws[1] = w_k; p.ws[2] = w_v; p.ws[3] = w_out;
    p.dstW = Wq;
    prep<<<dim3(256), 256, 0, stream>>>(p);

    // --- QKV projections (A = f32 inputs, conversion fused into staging) ---
    GArgs gq;
    gq.A[0] = xq;  gq.A[1] = xk;  gq.A[2] = xv;
    gq.W[0] = Wq;  gq.W[1] = Wk;  gq.W[2] = Wv;
    gq.C[0] = Q;   gq.C[1] = Kp;  gq.C[2] = Vt;
    gq.bias = nullptr;
    gq.modeT[0] = 0; gq.modeT[1] = 0; gq.modeT[2] = 1;
    gq.outf32 = 0; gq.af32 = 1;
    gemm_mfma<<<dim3(4, 64, 3), 256, 0, stream>>>(gq);

    // --- fused attention (128 queries/block, 8 waves) ---
    attn_mfma<<<dim3(8, 8, Mb), 512, 0, stream>>>(Q, Kp, Vt, tq, tk,
                                                  kw1, kb1, kw2, O);

    // --- output projection (A = O bf16 via gl_lds; f32 out + bias) ---
    GArgs go;
    go.A[0] = O;   go.A[1] = O;   go.A[2] = O;
    go.W[0] = Wo;  go.W[1] = Wo;  go.W[2] = Wo;
    go.C[0] = d_out; go.C[1] = d_out; go.C[2] = d_out;
    go.bias = b_out;
    go.modeT[0] = 0; go.modeT[1] = 0; go.modeT[2] = 0;
    go.outf32 = 1; go.af32 = 0;
    gemm_mfma<<<dim3(4, 64, 1), 256, 0, stream>>>(go);
}